// Round 5
// baseline (23301.497 us; speedup 1.0000x reference)
//
#include <hip/hip_runtime.h>

typedef _Float16 half8 __attribute__((ext_vector_type(8)));
typedef float f32x4 __attribute__((ext_vector_type(4)));

#define MFMA(a,b,c) __builtin_amdgcn_mfma_f32_16x16x32_f16((a),(b),(c),0,0,0)

// ---- packed-weight tile map (tile = 1KB = 16 outs x 32 K, f16) ----
//  B [0,3072):    w*384 + i*96 + kc*24 + q*6 + acc   (acc<3: W_ih r/z/n ; acc>=3: W_hh)
//  D [3072,3584): w*64 + i*16 + ks                   (W_o1[0:512,:])
//  E [3584,3648): w*16 + ks  (w<4)                   (W_o2)
//  X [3648,3904): nt*8 + ks                          (W_in[0:256,:])
//  C [3904,4160): nt*8 + ks                          (W_o1[512:768,:])
#define TB_D 3072
#define TB_E 3584
#define TB_X 3648
#define TB_C 3904

#define WS_ETAB (4160*1024)
#define WS_H0   (WS_ETAB + 64*512*4)
#define WS_XPRE ((size_t)WS_H0 + 1024*512*4)
#define WS_HPRE (WS_XPRE + (size_t)1024*128*512*2)
#define WS_NEED (WS_HPRE + (size_t)1024*128*512*2)

// ---------------- weight packing ----------------
__global__ void pack_k(const float* __restrict__ W_in, const float* __restrict__ W_ih,
                       const float* __restrict__ W_hh, const float* __restrict__ W_o1,
                       const float* __restrict__ W_o2, _Float16* __restrict__ pk)
{
  int ti = blockIdx.x, lane = threadIdx.x, lo = lane & 15;
  int sel = 0, n = 0, ks = 0;
  if (ti < TB_D){
    int w = ti/384, r = ti%384, i = r/96, r2 = r%96;
    int kc = r2/24, m = r2%24, q = m/6, acc = m%6;
    ks = kc*4 + q;
    int nn = (w*4 + i)*16 + lo;
    if (acc < 3){ n = acc*512 + nn; sel = 1; }
    else        { n = (acc-3)*512 + nn; sel = 2; }
  } else if (ti < TB_E){
    int r = ti - TB_D, w = r >> 6, r2 = r & 63, i = r2 >> 4; ks = r2 & 15;
    n = (w*4 + i)*16 + lo; sel = 3;
  } else if (ti < TB_X){
    int r = ti - TB_E, w = r >> 4; ks = r & 15;
    n = w*16 + lo; sel = 5;
  } else if (ti < TB_C){
    int r = ti - TB_X, nt = r >> 3; ks = r & 7;
    n = nt*16 + lo; sel = 0;
  } else {
    int r = ti - TB_C, nt = r >> 3; ks = r & 7;
    n = nt*16 + lo; sel = 4;
  }
  int kb = ks*32 + (lane >> 4)*8;
  half8 v;
  #pragma unroll
  for (int e = 0; e < 8; e++){
    int k = kb + e; float f;
    if      (sel == 0) f = W_in[k*512 + n];
    else if (sel == 1) f = W_ih[n*512 + k];
    else if (sel == 2) f = W_hh[n*512 + k];
    else if (sel == 3) f = W_o1[k*512 + n];
    else if (sel == 4) f = W_o1[(512 + k)*512 + n];
    else               f = W_o2[k*64 + n];
    v[e] = (_Float16)f;
  }
  *(half8*)(pk + (long)ti*512 + lane*8) = v;
}

// ---------------- Etab ----------------
__global__ void etab_k(const float* __restrict__ E, const float* __restrict__ W_in,
                       const float* __restrict__ b_in, float* __restrict__ Etab)
{
  int e = blockIdx.x, tid = threadIdx.x;
  __shared__ float er[256];
  if (tid < 256) er[tid] = E[e*256 + tid];
  __syncthreads();
  for (int j = tid; j < 512; j += 256){
    float acc = b_in[j];
    for (int k = 0; k < 256; k++) acc += er[k] * W_in[(256 + k)*512 + j];
    Etab[e*512 + j] = acc;
  }
}

// ---------------- h0 ----------------
__global__ __launch_bounds__(512) void h0_k(const float* __restrict__ ctx,
    const int* __restrict__ bh, const float* __restrict__ E,
    const float* __restrict__ W_init, const float* __restrict__ b_init,
    float* __restrict__ h0w)
{
  int b0 = blockIdx.x * 16, tid = threadIdx.x;
  __shared__ float cat[16][512];
  int c = tid & 255, rh = tid >> 8;
  for (int rr = 0; rr < 8; rr++){
    int r2 = rh*8 + rr;
    const float* p = ctx + ((b0 + r2)*128)*256 + c;
    float acc = 0.f;
    for (int t = 0; t < 128; t++) acc += p[t*256];
    cat[r2][c] = acc * (1.f/128.f);
    float s = 0.f;
    #pragma unroll
    for (int hh = 0; hh < 8; hh++){
      int e = bh[(b0 + r2)*8 + hh];
      s += E[e*256 + c];
    }
    cat[r2][256 + c] = s * 0.125f;
  }
  __syncthreads();
  int j = tid;
  float acc[16];
  #pragma unroll
  for (int r2 = 0; r2 < 16; r2++) acc[r2] = b_init[j];
  for (int k = 0; k < 512; k++){
    float wv = W_init[k*512 + j];
    #pragma unroll
    for (int r2 = 0; r2 < 16; r2++) acc[r2] += cat[r2][k] * wv;
  }
  #pragma unroll
  for (int r2 = 0; r2 < 16; r2++) h0w[(b0 + r2)*512 + j] = tanhf(acc[r2]);
}

// ---------------- prep: xpre = ctx@W_in_top, hpre = ctx@W_o1_bot (f16) ----------------
__global__ __launch_bounds__(512) void prep_k(const float* __restrict__ ctx,
    const _Float16* __restrict__ pk, _Float16* __restrict__ xpre,
    _Float16* __restrict__ hpre)
{
  int b = blockIdx.x, tid = threadIdx.x;
  int w = tid >> 6, lane = tid & 63, lo = lane & 15, hi = lane >> 4;
  extern __shared__ __align__(16) _Float16 A_lds[];   // 128 x 256 f16, swizzled (64KB)

  {
    int ra = tid >> 2, ca = (tid & 3)*64;
    const float* p = ctx + ((long)b*128 + ra)*256 + ca;
    #pragma unroll
    for (int c8 = 0; c8 < 8; c8++){
      float4 f0 = *(const float4*)(p + c8*8);
      float4 f1 = *(const float4*)(p + c8*8 + 4);
      half8 v;
      v[0]=(_Float16)f0.x; v[1]=(_Float16)f0.y; v[2]=(_Float16)f0.z; v[3]=(_Float16)f0.w;
      v[4]=(_Float16)f1.x; v[5]=(_Float16)f1.y; v[6]=(_Float16)f1.z; v[7]=(_Float16)f1.w;
      *(half8*)((char*)A_lds + (((ra*512 + (ca + c8*8)*2)) ^ ((ra&7)<<4))) = v;
    }
  }
  __syncthreads();

  const half8* PK64 = (const half8*)pk;
  const int regbase = (w < 4) ? TB_X : TB_C;
  _Float16* outp = (w < 4) ? xpre : hpre;
  const int colbase = (w & 3)*128;
  const int aswzp = (lo & 7) << 4;

  #pragma unroll 1
  for (int cth = 0; cth < 4; cth++){
    half8 bf0[8], bf1[8];
    #pragma unroll
    for (int ks = 0; ks < 8; ks++){
      bf0[ks] = PK64[(regbase + ((w&3)*8 + cth*2 + 0)*8 + ks)*64 + lane];
      bf1[ks] = PK64[(regbase + ((w&3)*8 + cth*2 + 1)*8 + ks)*64 + lane];
    }
    #pragma unroll 1
    for (int rt = 0; rt < 8; rt++){
      f32x4 acc0 = {0,0,0,0}, acc1 = {0,0,0,0};
      #pragma unroll
      for (int ks = 0; ks < 8; ks++){
        half8 a = *(const half8*)((const char*)A_lds +
                   ((((rt*16 + lo)*512 + hi*16 + ks*64)) ^ aswzp));
        acc0 = MFMA(a, bf0[ks], acc0);
        acc1 = MFMA(a, bf1[ks], acc1);
      }
      #pragma unroll
      for (int rr = 0; rr < 4; rr++){
        int t = rt*16 + hi*4 + rr;
        long rowoff = ((long)b*128 + t)*512 + colbase + cth*32;
        outp[rowoff +      lo] = (_Float16)acc0[rr];
        outp[rowoff + 16 + lo] = (_Float16)acc1[rr];
      }
    }
  }
}

// ================= main persistent scan: 64 WGs x 512 thr, 16 rows each =================
#define AFRAG(buf, base, ks) (*(const half8*)((const char*)(buf) + ((((base) + (ks)*64)) ^ aswz)))
#define WSTORE(buf, row, j, val) \
  *(_Float16*)((char*)(buf) + ((((row)*1024 + (j)*2)) ^ ((((row)&7))<<4))) = (_Float16)(val)
#define WSTORE8(buf, row, colf16, v8) \
  *(half8*)((char*)(buf) + ((((row)*1024 + (colf16)*2)) ^ ((((row)&7))<<4))) = (v8)

template<int PRE>
__global__ __launch_bounds__(512)
__attribute__((amdgpu_waves_per_eu(2,2)))
void main_k(
    const _Float16* __restrict__ pk, const float* __restrict__ Etab,
    const float* __restrict__ h0w, const float* __restrict__ ctx,
    const _Float16* __restrict__ xpre, const _Float16* __restrict__ hpre,
    const int* __restrict__ bh, const float* __restrict__ b_ih,
    const float* __restrict__ b_hh, const float* __restrict__ lng,
    const float* __restrict__ lnb, const float* __restrict__ b_o1,
    const float* __restrict__ b_o2, float* __restrict__ out)
{
  const int g = blockIdx.x, tid = threadIdx.x;
  const int w = tid >> 6, lane = tid & 63, lo = lane & 15, hi = lane >> 4;
  const int r0 = g*16;

  __shared__ __align__(16) _Float16 hbuf0[16*512]; // h / hn ping-pong
  __shared__ __align__(16) _Float16 hbuf1[16*512];
  __shared__ __align__(16) _Float16 xh_s [16*512]; // x, then hidden
  __shared__ __align__(16) _Float16 c_s  [16*256]; // ctx_t f16 (PRE=0 only)
  __shared__ float lg_s[16*64];
  __shared__ float stats[8][4][4][2];
  __shared__ float murs[16][2];
  __shared__ int   pb[16];

  float bcr[4], bcz[4], bin_[4], bhn[4], bo1v[4], lngv[4], lnbv[4];
  #pragma unroll
  for (int i = 0; i < 4; i++){
    int j = w*64 + i*16 + lo;
    bcr[i] = b_ih[j]     + b_hh[j];
    bcz[i] = b_ih[512+j] + b_hh[512+j];
    bin_[i]= b_ih[1024+j];
    bhn[i] = b_hh[1024+j];
    bo1v[i]= b_o1[j]; lngv[i]= lng[j]; lnbv[i]= lnb[j];
  }
  const float bo2v = (w < 4) ? b_o2[w*16 + lo] : 0.f;

  float hreg[4][4];
  #pragma unroll
  for (int i = 0; i < 4; i++)
    #pragma unroll
    for (int rr = 0; rr < 4; rr++)
      hreg[i][rr] = h0w[(r0 + hi*4 + rr)*512 + w*64 + i*16 + lo];

  #pragma unroll
  for (int c2 = 0; c2 < 2; c2++){
    int ch = tid*2 + c2, rr = ch >> 6, c8 = ch & 63;
    const float* p = h0w + (r0 + rr)*512 + c8*8;
    half8 v;
    #pragma unroll
    for (int e = 0; e < 8; e++) v[e] = (_Float16)p[e];
    *(half8*)((char*)hbuf0 + (((rr*1024 + c8*16)) ^ ((rr&7)<<4))) = v;
  }
  if (tid < 16) pb[tid] = bh[(r0 + tid)*8 + 7];
  __syncthreads();

  const int aswz  = (lo & 7) << 4;
  const int abase = lo*1024 + hi*16;
  const int cbase = lo*512  + hi*16;
  const half8* PK64 = (const half8*)pk;

  #pragma unroll 1
  for (int t = 0; t < 128; t++){
    _Float16* hbr = (t & 1) ? hbuf1 : hbuf0;
    _Float16* hbw = (t & 1) ? hbuf0 : hbuf1;

    // ---- A: build x = relu(xpre + Etab[pb]) (PRE=1) or stage ctx + gather et (PRE=0) ----
    float et[4][4];
    if (PRE){
      int rowA = tid >> 5, c32 = (tid & 31)*16;
      const _Float16* xp = xpre + (((long)(r0 + rowA)*128 + t)*512) + c32;
      half8 x0 = *(const half8*)xp;
      half8 x1 = *(const half8*)(xp + 8);
      const float* ep = Etab + pb[rowA]*512 + c32;
      float4 e0 = *(const float4*)(ep);
      float4 e1 = *(const float4*)(ep + 4);
      float4 e2 = *(const float4*)(ep + 8);
      float4 e3 = *(const float4*)(ep + 12);
      half8 o0, o1;
      o0[0]=(_Float16)fmaxf((float)x0[0]+e0.x,0.f); o0[1]=(_Float16)fmaxf((float)x0[1]+e0.y,0.f);
      o0[2]=(_Float16)fmaxf((float)x0[2]+e0.z,0.f); o0[3]=(_Float16)fmaxf((float)x0[3]+e0.w,0.f);
      o0[4]=(_Float16)fmaxf((float)x0[4]+e1.x,0.f); o0[5]=(_Float16)fmaxf((float)x0[5]+e1.y,0.f);
      o0[6]=(_Float16)fmaxf((float)x0[6]+e1.z,0.f); o0[7]=(_Float16)fmaxf((float)x0[7]+e1.w,0.f);
      o1[0]=(_Float16)fmaxf((float)x1[0]+e2.x,0.f); o1[1]=(_Float16)fmaxf((float)x1[1]+e2.y,0.f);
      o1[2]=(_Float16)fmaxf((float)x1[2]+e2.z,0.f); o1[3]=(_Float16)fmaxf((float)x1[3]+e2.w,0.f);
      o1[4]=(_Float16)fmaxf((float)x1[4]+e3.x,0.f); o1[5]=(_Float16)fmaxf((float)x1[5]+e3.y,0.f);
      o1[6]=(_Float16)fmaxf((float)x1[6]+e3.z,0.f); o1[7]=(_Float16)fmaxf((float)x1[7]+e3.w,0.f);
      WSTORE8(xh_s, rowA, c32,     o0);
      WSTORE8(xh_s, rowA, c32 + 8, o1);
    } else {
      int rr0 = tid >> 5, c8 = tid & 31;
      const float* cp = ctx + (((long)(r0 + rr0)*128 + t)*256) + c8*8;
      half8 v;
      #pragma unroll
      for (int e = 0; e < 8; e++) v[e] = (_Float16)cp[e];
      *(half8*)((char*)c_s + (((rr0*512 + c8*16)) ^ ((rr0&7)<<4))) = v;
      #pragma unroll
      for (int rr = 0; rr < 4; rr++){
        int e = pb[hi*4 + rr];
        #pragma unroll
        for (int i = 0; i < 4; i++) et[i][rr] = Etab[e*512 + w*64 + i*16 + lo];
      }
    }
    __syncthreads();

    // ---- A2 (PRE=0 only): x = relu(ctx @ W_in_top + et) ----
    if (!PRE){
      #pragma unroll
      for (int i = 0; i < 4; i++){
        const half8* xp_ = PK64 + (TB_X + (w*4+i)*8)*64 + lane;
        half8 xb[8];
        #pragma unroll
        for (int ks = 0; ks < 8; ks++) xb[ks] = xp_[ks*64];
        f32x4 acc = {0,0,0,0};
        #pragma unroll
        for (int ks = 0; ks < 8; ks++)
          acc = MFMA(AFRAG(c_s, cbase, ks), xb[ks], acc);
        #pragma unroll
        for (int rr = 0; rr < 4; rr++){
          int row = hi*4 + rr, jc = w*64 + i*16 + lo;
          WSTORE(xh_s, row, jc, fmaxf(acc[rr] + et[i][rr], 0.f));
        }
      }
      __syncthreads();
    }

    // ---- B: gi/gh (24-tile batches) + GRU gates ----
    {
      float srow[4] = {0,0,0,0}, sqrow[4] = {0,0,0,0};
      #pragma unroll
      for (int i = 0; i < 4; i++){
        f32x4 a0={0,0,0,0},a1={0,0,0,0},a2={0,0,0,0},a3={0,0,0,0},a4={0,0,0,0},a5={0,0,0,0};
        #pragma unroll
        for (int kc = 0; kc < 4; kc++){
          const half8* bp = PK64 + (w*384 + i*96 + kc*24)*64 + lane;
          half8 bb[24];
          #pragma unroll
          for (int m = 0; m < 24; m++) bb[m] = bp[m*64];
          half8 ax[4], ah[4];
          #pragma unroll
          for (int q = 0; q < 4; q++){
            ax[q] = AFRAG(xh_s, abase, kc*4 + q);
            ah[q] = AFRAG(hbr,  abase, kc*4 + q);
          }
          #pragma unroll
          for (int q = 0; q < 4; q++){
            a0 = MFMA(ax[q], bb[q*6+0], a0);
            a1 = MFMA(ax[q], bb[q*6+1], a1);
            a2 = MFMA(ax[q], bb[q*6+2], a2);
            a3 = MFMA(ah[q], bb[q*6+3], a3);
            a4 = MFMA(ah[q], bb[q*6+4], a4);
            a5 = MFMA(ah[q], bb[q*6+5], a5);
          }
        }
        #pragma unroll
        for (int rr = 0; rr < 4; rr++){
          float rg = 1.f/(1.f + __expf(-(a0[rr] + a3[rr] + bcr[i])));
          float zg = 1.f/(1.f + __expf(-(a1[rr] + a4[rr] + bcz[i])));
          float aa = (a2[rr] + bin_[i]) + rg*(a5[rr] + bhn[i]);
          float ea = __expf(-2.f*fabsf(aa));
          float th = (1.f - ea)/(1.f + ea);
          float ng = (aa < 0.f) ? -th : th;
          float hv = (1.f - zg)*ng + zg*hreg[i][rr];
          hreg[i][rr] = hv;
          srow[rr] += hv; sqrow[rr] += hv*hv;
        }
      }
      #pragma unroll
      for (int d = 1; d < 16; d <<= 1){
        #pragma unroll
        for (int rr = 0; rr < 4; rr++){
          srow[rr]  += __shfl_xor(srow[rr],  d);
          sqrow[rr] += __shfl_xor(sqrow[rr], d);
        }
      }
      if (lo == 0){
        #pragma unroll
        for (int rr = 0; rr < 4; rr++){
          stats[w][hi][rr][0] = srow[rr];
          stats[w][hi][rr][1] = sqrow[rr];
        }
      }
    }
    __syncthreads();
    if (w == 0 && lane < 16){
      float s = 0.f, q = 0.f;
      #pragma unroll
      for (int ww = 0; ww < 8; ww++){
        s += stats[ww][lane>>2][lane&3][0];
        q += stats[ww][lane>>2][lane&3][1];
      }
      float mu = s*(1.f/512.f);
      float var = q*(1.f/512.f) - mu*mu;
      murs[lane][0] = mu;
      murs[lane][1] = rsqrtf(var + 1e-5f);
    }
    __syncthreads();

    // ---- C: new h -> hbw, layernorm(h) -> hbr ----
    #pragma unroll
    for (int rr = 0; rr < 4; rr++){
      int row = hi*4 + rr;
      float mu = murs[row][0], rs = murs[row][1];
      #pragma unroll
      for (int i = 0; i < 4; i++){
        int jc = w*64 + i*16 + lo;
        float hv = hreg[i][rr];
        WSTORE(hbw, row, jc, hv);
        WSTORE(hbr, row, jc, (hv - mu)*rs*lngv[i] + lnbv[i]);
      }
    }
    __syncthreads();

    // ---- D: hidden = relu(hn @ W_o1_top + hpre(+ctx@W_o1_bot) + b_o1) ----
    #pragma unroll
    for (int i = 0; i < 4; i++){
      float hp[4];
      if (PRE){
        #pragma unroll
        for (int rr = 0; rr < 4; rr++){
          int row = hi*4 + rr;
          hp[rr] = (float)hpre[(((long)(r0 + row)*128 + t)*512) + w*64 + i*16 + lo];
        }
      }
      const half8* dp = PK64 + (TB_D + (w*4+i)*16)*64 + lane;
      half8 db[16];
      #pragma unroll
      for (int ks = 0; ks < 16; ks++) db[ks] = dp[ks*64];
      f32x4 acc = {0,0,0,0};
      #pragma unroll
      for (int ks = 0; ks < 16; ks++)
        acc = MFMA(AFRAG(hbr, abase, ks), db[ks], acc);
      if (!PRE){
        const half8* cp = PK64 + (TB_C + (w*4+i)*8)*64 + lane;
        half8 cb[8];
        #pragma unroll
        for (int ks = 0; ks < 8; ks++) cb[ks] = cp[ks*64];
        #pragma unroll
        for (int ks = 0; ks < 8; ks++)
          acc = MFMA(AFRAG(c_s, cbase, ks), cb[ks], acc);
      }
      #pragma unroll
      for (int rr = 0; rr < 4; rr++){
        int row = hi*4 + rr, jc = w*64 + i*16 + lo;
        float v = acc[rr] + bo1v[i] + (PRE ? hp[rr] : 0.f);
        WSTORE(xh_s, row, jc, fmaxf(v, 0.f));
      }
    }
    __syncthreads();

    // ---- E: logits = hidden @ W_o2 + b_o2 (waves 0-3) ----
    if (w < 4){
      const half8* ep_ = PK64 + (TB_E + w*16)*64 + lane;
      half8 eb[16];
      #pragma unroll
      for (int ks = 0; ks < 16; ks++) eb[ks] = ep_[ks*64];
      f32x4 acc = {0,0,0,0};
      #pragma unroll
      for (int ks = 0; ks < 16; ks++)
        acc = MFMA(AFRAG(xh_s, abase, ks), eb[ks], acc);
      #pragma unroll
      for (int rr = 0; rr < 4; rr++){
        int row = hi*4 + rr, jc = w*16 + lo;
        lg_s[row*64 + jc] = acc[rr] + bo2v;
      }
    }
    __syncthreads();

    // ---- F: out store + argmax (first-max tie rule), 2 rows per wave ----
    #pragma unroll
    for (int sub = 0; sub < 2; sub++){
      int r2 = w*2 + sub;
      float v = lg_s[r2*64 + lane];
      out[(((long)(r0 + r2))*128 + t)*64 + lane] = v;
      int idx = lane;
      #pragma unroll
      for (int d = 1; d < 64; d <<= 1){
        float ov = __shfl_xor(v, d);
        int oi = __shfl_xor(idx, d);
        if (ov > v || (ov == v && oi < idx)){ v = ov; idx = oi; }
      }
      if (lane == 0) pb[r2] = idx;
    }
    __syncthreads();
  }
}

extern "C" void kernel_launch(void* const* d_in, const int* in_sizes, int n_in,
                              void* d_out, int out_size, void* d_ws, size_t ws_size,
                              hipStream_t stream)
{
  const float* ctx    = (const float*)d_in[0];
  const int*   bh     = (const int*)d_in[1];
  const float* E      = (const float*)d_in[2];
  const float* W_in   = (const float*)d_in[3];
  const float* b_in   = (const float*)d_in[4];
  const float* W_init = (const float*)d_in[5];
  const float* b_init = (const float*)d_in[6];
  const float* W_ih   = (const float*)d_in[7];
  const float* W_hh   = (const float*)d_in[8];
  const float* b_ih   = (const float*)d_in[9];
  const float* b_hh   = (const float*)d_in[10];
  const float* ln_g   = (const float*)d_in[11];
  const float* ln_b   = (const float*)d_in[12];
  const float* W_o1   = (const float*)d_in[13];
  const float* b_o1   = (const float*)d_in[14];
  const float* W_o2   = (const float*)d_in[15];
  const float* b_o2   = (const float*)d_in[16];
  float* out = (float*)d_out;

  _Float16* pk   = (_Float16*)d_ws;
  float*    Etab = (float*)((char*)d_ws + WS_ETAB);
  float*    h0w  = (float*)((char*)d_ws + WS_H0);
  _Float16* xpre = (_Float16*)((char*)d_ws + WS_XPRE);
  _Float16* hpre = (_Float16*)((char*)d_ws + WS_HPRE);

  hipLaunchKernelGGL(pack_k, dim3(4160), dim3(64), 0, stream, W_in, W_ih, W_hh, W_o1, W_o2, pk);
  hipLaunchKernelGGL(etab_k, dim3(64), dim3(256), 0, stream, E, W_in, b_in, Etab);
  hipLaunchKernelGGL(h0_k, dim3(64), dim3(512), 0, stream, ctx, bh, E, W_init, b_init, h0w);

  if (ws_size >= WS_NEED){
    (void)hipFuncSetAttribute((const void*)prep_k,
        hipFuncAttributeMaxDynamicSharedMemorySize, 65536);
    hipLaunchKernelGGL(prep_k, dim3(1024), dim3(512), 65536, stream, ctx, pk, xpre, hpre);
    hipLaunchKernelGGL(HIP_KERNEL_NAME(main_k<1>), dim3(64), dim3(512), 0, stream,
                       pk, Etab, h0w, ctx, xpre, hpre, bh,
                       b_ih, b_hh, ln_g, ln_b, b_o1, b_o2, out);
  } else {
    hipLaunchKernelGGL(HIP_KERNEL_NAME(main_k<0>), dim3(64), dim3(512), 0, stream,
                       pk, Etab, h0w, ctx, (const _Float16*)nullptr, (const _Float16*)nullptr, bh,
                       b_ih, b_hh, ln_g, ln_b, b_o1, b_o2, out);
  }
}

// Round 9
// 8327.799 us; speedup vs baseline: 2.7980x; 2.7980x over previous
//
#include <hip/hip_runtime.h>

typedef _Float16 half8 __attribute__((ext_vector_type(8)));
typedef float f32x4 __attribute__((ext_vector_type(4)));

#define MFMA(a,b,c) __builtin_amdgcn_mfma_f32_16x16x32_f16((a),(b),(c),0,0,0)

// ---- workspace map (bytes) ----
#define PKW_BYTES ((size_t)(4*468 + 4*456)*1024)        // 3,784,704
#define OFF_ETAB  PKW_BYTES                             // Etab f32: 131,072
#define OFF_H0    (OFF_ETAB + (size_t)64*512*4)         // h0 f32: 2,097,152
#define OFF_XPRE  (OFF_H0 + (size_t)1024*512*4)
#define OFF_HPRE  (OFF_XPRE + (size_t)1024*128*512*2)
// end = 274,448,384 bytes  (< proven ws floor 274,923,520)

__device__ __forceinline__ void gll16(const void* g, void* l){
  __builtin_amdgcn_global_load_lds(
      (const __attribute__((address_space(1))) void*)g,
      (__attribute__((address_space(3))) void*)l, 16, 0, 0);
}

// ======= packw: per-wave stream, consumption order =======
// ts<384: B: ts = i*96 + kq*6 + acc (ks=kq; acc<3 -> W_ih r/z/n; else W_hh)
// ts in [384,448): D: td=ts-384: i=td>>4, ks=td&15 (W_o1 top);  [448,450): pad
// w<4: ts in [450,466): E: te=ts-450 (W_o2); [466,468): pad
// w>=4: ts in [450,456): pad; stream ends at 456
__global__ void packw_k(const float* __restrict__ W_ih, const float* __restrict__ W_hh,
                        const float* __restrict__ W_o1, const float* __restrict__ W_o2,
                        _Float16* __restrict__ pkw)
{
  int ts = blockIdx.x, w = blockIdx.y;
  if (w >= 4 && ts >= 456) return;
  int lane = threadIdx.x, lo = lane & 15, kb8 = (lane >> 4)*8;
  half8 v;
  #pragma unroll
  for (int e = 0; e < 8; e++) v[e] = (_Float16)0.f;
  if (ts < 384){
    int i = ts/96, r = ts%96, kc = r/24, m = r%24, q = m/6, acc = m%6;
    int ks = kc*4 + q, nn = (w*4 + i)*16 + lo;
    #pragma unroll
    for (int e = 0; e < 8; e++){
      int k = ks*32 + kb8 + e;
      v[e] = (acc < 3) ? (_Float16)W_ih[(acc*512 + nn)*512 + k]
                       : (_Float16)W_hh[((acc-3)*512 + nn)*512 + k];
    }
  } else if (ts < 448){
    int td = ts - 384;
    int i = td >> 4, ks = td & 15, n = (w*4 + i)*16 + lo;
    #pragma unroll
    for (int e = 0; e < 8; e++) v[e] = (_Float16)W_o1[(ks*32 + kb8 + e)*512 + n];
  } else if (ts >= 450 && ts < 466 && w < 4){
    int te = ts - 450, n = w*16 + lo;
    #pragma unroll
    for (int e = 0; e < 8; e++) v[e] = (_Float16)W_o2[(te*32 + kb8 + e)*64 + n];
  }
  long base = (w < 4) ? (long)w*468 : (long)1872 + (long)(w-4)*456;
  *(half8*)(pkw + (base + ts)*512 + lane*8) = v;
}

// ---------------- Etab (f32) ----------------
__global__ void etab_k(const float* __restrict__ E, const float* __restrict__ W_in,
                       const float* __restrict__ b_in, float* __restrict__ Etab)
{
  int e = blockIdx.x, tid = threadIdx.x;
  __shared__ float er[256];
  if (tid < 256) er[tid] = E[e*256 + tid];
  __syncthreads();
  for (int j = tid; j < 512; j += 256){
    float acc = b_in[j];
    for (int k = 0; k < 256; k++) acc += er[k] * W_in[(256 + k)*512 + j];
    Etab[e*512 + j] = acc;
  }
}

// ---------------- h0 (f32) ----------------
__global__ __launch_bounds__(512) void h0_k(const float* __restrict__ ctx,
    const int* __restrict__ bh, const float* __restrict__ E,
    const float* __restrict__ W_init, const float* __restrict__ b_init,
    float* __restrict__ h0w)
{
  int b0 = blockIdx.x * 16, tid = threadIdx.x;
  __shared__ float cat[16][512];
  int c = tid & 255, rh = tid >> 8;
  for (int rr = 0; rr < 8; rr++){
    int r2 = rh*8 + rr;
    const float* p = ctx + ((b0 + r2)*128)*256 + c;
    float acc = 0.f;
    for (int t = 0; t < 128; t++) acc += p[t*256];
    cat[r2][c] = acc * (1.f/128.f);
    float s = 0.f;
    #pragma unroll
    for (int hh = 0; hh < 8; hh++){
      int e = bh[(b0 + r2)*8 + hh];
      s += E[e*256 + c];
    }
    cat[r2][256 + c] = s * 0.125f;
  }
  __syncthreads();
  int j = tid;
  float acc[16];
  #pragma unroll
  for (int r2 = 0; r2 < 16; r2++) acc[r2] = b_init[j];
  for (int k = 0; k < 512; k++){
    float wv = W_init[k*512 + j];
    #pragma unroll
    for (int r2 = 0; r2 < 16; r2++) acc[r2] += cat[r2][k] * wv;
  }
  #pragma unroll
  for (int r2 = 0; r2 < 16; r2++) h0w[(b0 + r2)*512 + j] = tanhf(acc[r2]);
}

// ---------------- prep: xpre = ctx@W_in_top, hpre = ctx@W_o1_bot (f16 out) ----------------
__global__ __launch_bounds__(512) void prep_k(const float* __restrict__ ctx,
    const float* __restrict__ W_in, const float* __restrict__ W_o1,
    _Float16* __restrict__ xpre, _Float16* __restrict__ hpre)
{
  int b = blockIdx.x, tid = threadIdx.x;
  int w = tid >> 6, lane = tid & 63, lo = lane & 15, hi = lane >> 4;
  extern __shared__ __align__(16) _Float16 A_lds[];   // 128 x 256 f16, swizzled

  {
    int ra = tid >> 2, ca = (tid & 3)*64;
    const float* p = ctx + ((long)b*128 + ra)*256 + ca;
    #pragma unroll
    for (int c8 = 0; c8 < 8; c8++){
      float4 f0 = *(const float4*)(p + c8*8);
      float4 f1 = *(const float4*)(p + c8*8 + 4);
      half8 v;
      v[0]=(_Float16)f0.x; v[1]=(_Float16)f0.y; v[2]=(_Float16)f0.z; v[3]=(_Float16)f0.w;
      v[4]=(_Float16)f1.x; v[5]=(_Float16)f1.y; v[6]=(_Float16)f1.z; v[7]=(_Float16)f1.w;
      *(half8*)((char*)A_lds + (((ra*512 + (ca + c8*8)*2)) ^ ((ra&7)<<4))) = v;
    }
  }
  __syncthreads();

  const float* Wb = (w < 4) ? W_in : (W_o1 + 512*512);
  _Float16* outp = (w < 4) ? xpre : hpre;
  const int colbase = (w & 3)*128;
  const int aswzp = (lo & 7) << 4;

  #pragma unroll 1
  for (int cth = 0; cth < 4; cth++){
    half8 bf0[8], bf1[8];
    const int n0 = colbase + cth*32 + lo;
    #pragma unroll
    for (int ks = 0; ks < 8; ks++){
      const int kb = ks*32 + hi*8;
      half8 v0, v1;
      #pragma unroll
      for (int e = 0; e < 8; e++){
        v0[e] = (_Float16)Wb[(kb + e)*512 + n0];
        v1[e] = (_Float16)Wb[(kb + e)*512 + n0 + 16];
      }
      bf0[ks] = v0; bf1[ks] = v1;
    }
    #pragma unroll 1
    for (int rt = 0; rt < 8; rt++){
      f32x4 acc0 = {0,0,0,0}, acc1 = {0,0,0,0};
      #pragma unroll
      for (int ks = 0; ks < 8; ks++){
        half8 a = *(const half8*)((const char*)A_lds +
                   ((((rt*16 + lo)*512 + hi*16 + ks*64)) ^ aswzp));
        acc0 = MFMA(a, bf0[ks], acc0);
        acc1 = MFMA(a, bf1[ks], acc1);
      }
      #pragma unroll
      for (int rr = 0; rr < 4; rr++){
        int t = rt*16 + hi*4 + rr;
        long rowoff = ((long)b*128 + t)*512 + colbase + cth*32;
        outp[rowoff +      lo] = (_Float16)acc0[rr];
        outp[rowoff + 16 + lo] = (_Float16)acc1[rr];
      }
    }
  }
}

// ================= main: 64 WGs x 512 thr; LDS ring, per-chunk vmcnt(0) drains =================
#define AFRAG(buf, base, ks) (*(const half8*)((const char*)(buf) + ((((base) + (ks)*64)) ^ aswz)))
#define WSTORE(buf, row, j, val) \
  *(_Float16*)((char*)(buf) + ((((row)*1024 + (j)*2)) ^ ((((row)&7))<<4))) = (_Float16)(val)
#define WSTORE8(buf, row, colf16, v8) \
  *(half8*)((char*)(buf) + ((((row)*1024 + (colf16)*2)) ^ ((((row)&7))<<4))) = (v8)

#define DRAIN do{ asm volatile("s_waitcnt vmcnt(0)" ::: "memory"); \
                  __builtin_amdgcn_sched_barrier(0); }while(0)

#define ISSUE(p_) do{ \
    const char* s_ = pkw_w + ((long)(p_))*6144 + (lane<<4); \
    char* d_ = ring + ((((p_)&1)*8 + w)*6144); \
    gll16(s_,        d_); \
    gll16(s_ + 1024, d_ + 1024); \
    gll16(s_ + 2048, d_ + 2048); \
    gll16(s_ + 3072, d_ + 3072); \
    gll16(s_ + 4096, d_ + 4096); \
    gll16(s_ + 5120, d_ + 5120); \
    __builtin_amdgcn_sched_barrier(0); \
  }while(0)

#define RFR(p_, f_) (*(const half8*)(ring + ((((p_)&1)*8 + w)*6144) + ((f_)<<10) + (lane<<4)))

__global__ __launch_bounds__(512) void main2_k(
    const _Float16* __restrict__ pkw, const float* __restrict__ Etab,
    const float* __restrict__ h0w, const _Float16* __restrict__ xpre,
    const _Float16* __restrict__ hpre, const int* __restrict__ bh,
    const float* __restrict__ b_ih, const float* __restrict__ b_hh,
    const float* __restrict__ lng, const float* __restrict__ lnb,
    const float* __restrict__ b_o1, const float* __restrict__ b_o2,
    float* __restrict__ out)
{
  const int g = blockIdx.x, tid = threadIdx.x;
  const int w = tid >> 6, lane = tid & 63, lo = lane & 15, hi = lane >> 4;
  const int r0 = g*16;

  extern __shared__ __align__(16) char smem[];
  char*      ring = smem;                          // 2 slots x 8 waves x 6144 = 98304
  _Float16*  h_s  = (_Float16*)(smem + 98304);
  _Float16*  hn_s = (_Float16*)(smem + 114688);
  _Float16*  xh_s = (_Float16*)(smem + 131072);
  float*     lg_s = (float*)(smem + 147456);
  float*     stats= (float*)(smem + 151552);
  float*     murs = (float*)(smem + 152576);
  int*       pb   = (int*)(smem + 152704);

  float bcr[4], bcz[4], bin_[4], bhn[4], bo1v[4], lngv[4], lnbv[4];
  #pragma unroll
  for (int i = 0; i < 4; i++){
    int j = w*64 + i*16 + lo;
    bcr[i] = b_ih[j]     + b_hh[j];
    bcz[i] = b_ih[512+j] + b_hh[512+j];
    bin_[i]= b_ih[1024+j];
    bhn[i] = b_hh[1024+j];
    bo1v[i]= b_o1[j]; lngv[i]= lng[j]; lnbv[i]= lnb[j];
  }
  const float bo2v = (w < 4) ? b_o2[w*16 + lo] : 0.f;

  float hreg[4][4];
  #pragma unroll
  for (int i = 0; i < 4; i++)
    #pragma unroll
    for (int rr = 0; rr < 4; rr++)
      hreg[i][rr] = h0w[(r0 + hi*4 + rr)*512 + w*64 + i*16 + lo];

  #pragma unroll
  for (int c2 = 0; c2 < 2; c2++){
    int ch = tid*2 + c2, rr = ch >> 6, c8 = ch & 63;
    const float* p = h0w + (r0 + rr)*512 + c8*8;
    half8 v;
    #pragma unroll
    for (int e = 0; e < 8; e++) v[e] = (_Float16)p[e];
    *(half8*)((char*)h_s + (((rr*1024 + c8*16)) ^ ((rr&7)<<4))) = v;
  }
  if (tid < 16) pb[tid] = bh[(r0 + tid)*8 + 7];

  const int aswz  = (lo & 7) << 4;
  const int abase = lo*1024 + hi*16;
  const char* pkw_w = (const char*)pkw +
      ((w < 4) ? (long)w*468*1024 : ((long)1872 + (long)(w-4)*456)*1024);

  ISSUE(0);
  __syncthreads();   // drains vmcnt(0): chunk 0 resident before loop

  #pragma unroll 1
  for (int t = 0; t < 128; t++){
    // ---- A: x = relu(xpre + Etab[pb]) -> xh_s (round-5 exact math) ----
    {
      int rowA = tid >> 5, c32 = (tid & 31)*16;
      const _Float16* xp = xpre + (((long)(r0 + rowA)*128 + t)*512) + c32;
      half8 x0 = ((const half8*)xp)[0];
      half8 x1 = ((const half8*)xp)[1];
      const float* ep = Etab + pb[rowA]*512 + c32;
      float4 e0 = *(const float4*)(ep);
      float4 e1 = *(const float4*)(ep + 4);
      float4 e2 = *(const float4*)(ep + 8);
      float4 e3 = *(const float4*)(ep + 12);
      half8 o0, o1;
      o0[0]=(_Float16)fmaxf((float)x0[0]+e0.x,0.f); o0[1]=(_Float16)fmaxf((float)x0[1]+e0.y,0.f);
      o0[2]=(_Float16)fmaxf((float)x0[2]+e0.z,0.f); o0[3]=(_Float16)fmaxf((float)x0[3]+e0.w,0.f);
      o0[4]=(_Float16)fmaxf((float)x0[4]+e1.x,0.f); o0[5]=(_Float16)fmaxf((float)x0[5]+e1.y,0.f);
      o0[6]=(_Float16)fmaxf((float)x0[6]+e1.z,0.f); o0[7]=(_Float16)fmaxf((float)x0[7]+e1.w,0.f);
      o1[0]=(_Float16)fmaxf((float)x1[0]+e2.x,0.f); o1[1]=(_Float16)fmaxf((float)x1[1]+e2.y,0.f);
      o1[2]=(_Float16)fmaxf((float)x1[2]+e2.z,0.f); o1[3]=(_Float16)fmaxf((float)x1[3]+e2.w,0.f);
      o1[4]=(_Float16)fmaxf((float)x1[4]+e3.x,0.f); o1[5]=(_Float16)fmaxf((float)x1[5]+e3.y,0.f);
      o1[6]=(_Float16)fmaxf((float)x1[6]+e3.z,0.f); o1[7]=(_Float16)fmaxf((float)x1[7]+e3.w,0.f);
      WSTORE8(xh_s, rowA, c32,     o0);
      WSTORE8(xh_s, rowA, c32 + 8, o1);
    }
    __syncthreads();

    // ---- B: chunks 0..63 (issue p+1, consume p from drained slot, drain) ----
    float srow[4] = {0,0,0,0}, sqrow[4] = {0,0,0,0};
    #pragma unroll 1
    for (int i = 0; i < 4; i++){
      f32x4 a0={0,0,0,0},a1={0,0,0,0},a2={0,0,0,0},a3={0,0,0,0},a4={0,0,0,0},a5={0,0,0,0};
      #pragma unroll
      for (int kq = 0; kq < 16; kq++){
        const int p = i*16 + kq;
        ISSUE(p + 1);
        half8 ax = AFRAG(xh_s, abase, kq);
        half8 ah = AFRAG(h_s,  abase, kq);
        a0 = MFMA(ax, RFR(p,0), a0);
        a1 = MFMA(ax, RFR(p,1), a1);
        a2 = MFMA(ax, RFR(p,2), a2);
        a3 = MFMA(ah, RFR(p,3), a3);
        a4 = MFMA(ah, RFR(p,4), a4);
        a5 = MFMA(ah, RFR(p,5), a5);
        DRAIN;
      }
      #pragma unroll
      for (int rr = 0; rr < 4; rr++){
        float rg = 1.f/(1.f + __expf(-(a0[rr] + a3[rr] + bcr[i])));
        float zg = 1.f/(1.f + __expf(-(a1[rr] + a4[rr] + bcz[i])));
        float aa = (a2[rr] + bin_[i]) + rg*(a5[rr] + bhn[i]);
        float ea = __expf(-2.f*fabsf(aa));
        float th = (1.f - ea)/(1.f + ea);
        float ng = (aa < 0.f) ? -th : th;
        float hv = (1.f - zg)*ng + zg*hreg[i][rr];
        hreg[i][rr] = hv;
        srow[rr] += hv; sqrow[rr] += hv*hv;
      }
    }
    #pragma unroll
    for (int d = 1; d < 16; d <<= 1){
      #pragma unroll
      for (int rr = 0; rr < 4; rr++){
        srow[rr]  += __shfl_xor(srow[rr],  d);
        sqrow[rr] += __shfl_xor(sqrow[rr], d);
      }
    }
    if (lo == 0){
      #pragma unroll
      for (int rr = 0; rr < 4; rr++){
        stats[((w*4 + hi)*4 + rr)*2 + 0] = srow[rr];
        stats[((w*4 + hi)*4 + rr)*2 + 1] = sqrow[rr];
      }
    }
    __syncthreads();
    if (w == 0 && lane < 16){
      float s = 0.f, q = 0.f;
      #pragma unroll
      for (int ww = 0; ww < 8; ww++){
        s += stats[((ww*4 + (lane>>2))*4 + (lane&3))*2 + 0];
        q += stats[((ww*4 + (lane>>2))*4 + (lane&3))*2 + 1];
      }
      float mu = s*(1.f/512.f);
      float var = q*(1.f/512.f) - mu*mu;
      murs[lane*2 + 0] = mu;
      murs[lane*2 + 1] = rsqrtf(var + 1e-5f);
    }
    __syncthreads();

    // ---- C: h -> h_s, layernorm(h) -> hn_s; hpre gather ----
    float hp[4][4];
    #pragma unroll
    for (int rr = 0; rr < 4; rr++){
      int row = hi*4 + rr;
      float mu = murs[row*2 + 0], rs = murs[row*2 + 1];
      #pragma unroll
      for (int i = 0; i < 4; i++){
        int jc = w*64 + i*16 + lo;
        float hv = hreg[i][rr];
        WSTORE(h_s,  row, jc, hv);
        WSTORE(hn_s, row, jc, (hv - mu)*rs*lngv[i] + lnbv[i]);
        hp[i][rr] = (float)hpre[(((long)(r0 + row)*128 + t)*512) + jc];
      }
    }
    __syncthreads();

    // ---- D: chunks 64..74 (64 real frags + 2 pad) ----
    {
      f32x4 d0={0,0,0,0}, d1={0,0,0,0}, d2={0,0,0,0}, d3={0,0,0,0};
      #pragma unroll
      for (int c = 0; c < 11; c++){
        ISSUE(65 + c);
        #pragma unroll
        for (int f = 0; f < 6; f++){
          const int td = c*6 + f;
          if (td < 64){
            const int ii = td >> 4, ks = td & 15;
            half8 a = AFRAG(hn_s, abase, ks);
            half8 bf = RFR(64 + c, f);
            if      (ii == 0) d0 = MFMA(a, bf, d0);
            else if (ii == 1) d1 = MFMA(a, bf, d1);
            else if (ii == 2) d2 = MFMA(a, bf, d2);
            else              d3 = MFMA(a, bf, d3);
          }
        }
        DRAIN;
      }
      #pragma unroll
      for (int rr = 0; rr < 4; rr++){
        int row = hi*4 + rr;
        WSTORE(xh_s, row, w*64 +  0 + lo, fmaxf(d0[rr] + bo1v[0] + hp[0][rr], 0.f));
        WSTORE(xh_s, row, w*64 + 16 + lo, fmaxf(d1[rr] + bo1v[1] + hp[1][rr], 0.f));
        WSTORE(xh_s, row, w*64 + 32 + lo, fmaxf(d2[rr] + bo1v[2] + hp[2][rr], 0.f));
        WSTORE(xh_s, row, w*64 + 48 + lo, fmaxf(d3[rr] + bo1v[3] + hp[3][rr], 0.f));
      }
    }
    __syncthreads();

    // ---- E: w<4: chunks 75..77 (16 real + 2 pad); w>=4: prefetch chunk 0 ----
    if (w < 4){
      f32x4 eacc = {0,0,0,0};
      #pragma unroll
      for (int c = 0; c < 3; c++){
        const int pn = (c == 2) ? 0 : (76 + c);
        ISSUE(pn);
        #pragma unroll
        for (int f = 0; f < 6; f++){
          const int te = c*6 + f;
          if (te < 16)
            eacc = MFMA(AFRAG(xh_s, abase, te), RFR(75 + c, f), eacc);
        }
        DRAIN;
      }
      #pragma unroll
      for (int rr = 0; rr < 4; rr++){
        int row = hi*4 + rr;
        lg_s[row*64 + w*16 + lo] = eacc[rr] + bo2v;
      }
    } else {
      ISSUE(0);
      DRAIN;
    }
    __syncthreads();

    // ---- F: out store + argmax (first-max tie), 2 rows/wave ----
    #pragma unroll
    for (int sub = 0; sub < 2; sub++){
      int r2 = w*2 + sub;
      float v = lg_s[r2*64 + lane];
      out[(((long)(r0 + r2))*128 + t)*64 + lane] = v;
      int idx = lane;
      #pragma unroll
      for (int d = 1; d < 64; d <<= 1){
        float ov = __shfl_xor(v, d);
        int oi = __shfl_xor(idx, d);
        if (ov > v || (ov == v && oi < idx)){ v = ov; idx = oi; }
      }
      if (lane == 0) pb[r2] = idx;
    }
    __syncthreads();
  }
}

extern "C" void kernel_launch(void* const* d_in, const int* in_sizes, int n_in,
                              void* d_out, int out_size, void* d_ws, size_t ws_size,
                              hipStream_t stream)
{
  const float* ctx    = (const float*)d_in[0];
  const int*   bh     = (const int*)d_in[1];
  const float* E      = (const float*)d_in[2];
  const float* W_in   = (const float*)d_in[3];
  const float* b_in   = (const float*)d_in[4];
  const float* W_init = (const float*)d_in[5];
  const float* b_init = (const float*)d_in[6];
  const float* W_ih   = (const float*)d_in[7];
  const float* W_hh   = (const float*)d_in[8];
  const float* b_ih   = (const float*)d_in[9];
  const float* b_hh   = (const float*)d_in[10];
  const float* ln_g   = (const float*)d_in[11];
  const float* ln_b   = (const float*)d_in[12];
  const float* W_o1   = (const float*)d_in[13];
  const float* b_o1   = (const float*)d_in[14];
  const float* W_o2   = (const float*)d_in[15];
  const float* b_o2   = (const float*)d_in[16];
  float* out = (float*)d_out;

  _Float16* pkw  = (_Float16*)d_ws;
  float*    Etab = (float*)((char*)d_ws + OFF_ETAB);
  float*    h0w  = (float*)((char*)d_ws + OFF_H0);
  _Float16* xpre = (_Float16*)((char*)d_ws + OFF_XPRE);
  _Float16* hpre = (_Float16*)((char*)d_ws + OFF_HPRE);

  (void)hipFuncSetAttribute((const void*)prep_k,
      hipFuncAttributeMaxDynamicSharedMemorySize, 65536);
  (void)hipFuncSetAttribute((const void*)main2_k,
      hipFuncAttributeMaxDynamicSharedMemorySize, 152768);

  hipLaunchKernelGGL(packw_k, dim3(468, 8), dim3(64), 0, stream, W_ih, W_hh, W_o1, W_o2, pkw);
  hipLaunchKernelGGL(etab_k, dim3(64), dim3(256), 0, stream, E, W_in, b_in, Etab);
  hipLaunchKernelGGL(h0_k, dim3(64), dim3(512), 0, stream, ctx, bh, E, W_init, b_init, h0w);
  hipLaunchKernelGGL(prep_k, dim3(1024), dim3(512), 65536, stream, ctx, W_in, W_o1, xpre, hpre);
  hipLaunchKernelGGL(main2_k, dim3(64), dim3(512), 152768, stream,
                     pkw, Etab, h0w, xpre, hpre, bh,
                     b_ih, b_hh, ln_g, ln_b, b_o1, b_o2, out);
}